// Round 1
// baseline (29.131 us; speedup 1.0000x reference)
//
#include <hip/hip_runtime.h>

#define DIM 7
#define HD  32   // hidden width of W1
#define P2  21   // C(7,2)
#define P3  35   // C(7,3)
#define BLK 256

// Lexicographic triples (i<j<k) from 7 — combination index -> (i,j,k)
static __device__ const int TI[P3] = {
  0,0,0,0,0,0,0,0,0,0,0,0,0,0,0,
  1,1,1,1,1,1,1,1,1,1,
  2,2,2,2,2,2,
  3,3,3,
  4};
static __device__ const int TJ[P3] = {
  1,1,1,1,1, 2,2,2,2, 3,3,3, 4,4, 5,
  2,2,2,2, 3,3,3, 4,4, 5,
  3,3,3, 4,4, 5,
  4,4, 5,
  5};
static __device__ const int TK[P3] = {
  2,3,4,5,6, 3,4,5,6, 4,5,6, 5,6, 6,
  3,4,5,6, 4,5,6, 5,6, 6,
  4,5,6, 5,6, 6,
  5,6, 6,
  6};

// pair index in lexicographic C(7,2) enumeration, a<b
__device__ __forceinline__ int pos2(int a, int b) {
  return a * 6 - (a * (a - 1)) / 2 + (b - a - 1);
}

__global__ __launch_bounds__(BLK)
void dform_kernel(const float* __restrict__ x,
                  const float* __restrict__ W1,
                  const float* __restrict__ W2,
                  float* __restrict__ out, int B)
{
  __shared__ float sW1[DIM * HD];        // 224 floats
  __shared__ float sM[HD][P3 + 1];       // 32 x 36 (padded rows, 16B-aligned)
  __shared__ float stage[BLK * P3];      // 8960 floats; reused for x then out

  const int tid = threadIdx.x;

  // --- load W1 into LDS ---
  for (int i = tid; i < DIM * HD; i += BLK) sW1[i] = W1[i];

  // --- build M[h][o] = W1[i,h]*W2[h,jk] - W1[j,h]*W2[h,ik] + W1[k,h]*W2[h,ij] ---
  for (int e = tid; e < HD * P3; e += BLK) {
    int h = e / P3;
    int o = e - h * P3;
    int i = TI[o], j = TJ[o], k = TK[o];
    float v = W1[i * HD + h] * W2[h * P2 + pos2(j, k)]
            - W1[j * HD + h] * W2[h * P2 + pos2(i, k)]
            + W1[k * HD + h] * W2[h * P2 + pos2(i, j)];
    sM[h][o] = v;
  }

  const long long base = (long long)blockIdx.x * BLK;
  int rows = B - (int)base;
  if (rows > BLK) rows = BLK;

  // --- stage x rows into LDS (coalesced float4 for full blocks) ---
  if (rows == BLK) {
    const float4* src = reinterpret_cast<const float4*>(x + base * DIM);
    float4* dst = reinterpret_cast<float4*>(stage);
    #pragma unroll
    for (int i = tid; i < BLK * DIM / 4; i += BLK) dst[i] = src[i];
  } else {
    for (int i = tid; i < rows * DIM; i += BLK) stage[i] = x[base * DIM + i];
  }
  __syncthreads();

  // per-thread row of x (stride 7 -> gcd(7,32)=1 -> conflict-free)
  float xr[DIM];
  #pragma unroll
  for (int j = 0; j < DIM; ++j) xr[j] = stage[tid * DIM + j];

  float acc[P3];
  #pragma unroll
  for (int p = 0; p < P3; ++p) acc[p] = 0.f;

  if (tid < rows) {
    for (int h = 0; h < HD; ++h) {
      float t = 0.f;
      #pragma unroll
      for (int j = 0; j < DIM; ++j) t = fmaf(xr[j], sW1[j * HD + h], t);
      float c = __cosf(t);
      #pragma unroll
      for (int p = 0; p < P3; ++p) acc[p] = fmaf(c, sM[h][p], acc[p]);
    }
  }
  __syncthreads();  // everyone done reading stage-as-x

  if (tid < rows) {
    #pragma unroll
    for (int p = 0; p < P3; ++p) stage[tid * P3 + p] = acc[p];  // stride 35: conflict-free
  }
  __syncthreads();

  // --- coalesced store ---
  if (rows == BLK) {
    float4* dst = reinterpret_cast<float4*>(out + base * P3);
    const float4* src = reinterpret_cast<const float4*>(stage);
    for (int i = tid; i < BLK * P3 / 4; i += BLK) dst[i] = src[i];
  } else {
    for (int i = tid; i < rows * P3; i += BLK) out[base * P3 + i] = stage[i];
  }
}

extern "C" void kernel_launch(void* const* d_in, const int* in_sizes, int n_in,
                              void* d_out, int out_size, void* d_ws, size_t ws_size,
                              hipStream_t stream) {
  const float* x  = (const float*)d_in[0];
  const float* W1 = (const float*)d_in[1];
  const float* W2 = (const float*)d_in[2];
  float* out = (float*)d_out;
  const int B = in_sizes[0] / DIM;
  const int grid = (B + BLK - 1) / BLK;
  hipLaunchKernelGGL(dform_kernel, dim3(grid), dim3(BLK), 0, stream,
                     x, W1, W2, out, B);
}

// Round 3
// 27.318 us; speedup vs baseline: 1.0663x; 1.0663x over previous
//
#include <hip/hip_runtime.h>

#define DIM 7
#define HD  32   // hidden width of W1
#define P2  21   // C(7,2)
#define P3  35   // C(7,3)
#define BLK 256
#define RSTR 64  // dwords per h-row in cbuf: [0..6]=W1T, [16..50]=M row. 256B rows.

// Lexicographic triples (i<j<k) from 7 — combination index -> (i,j,k)
static __device__ const int TI[P3] = {
  0,0,0,0,0,0,0,0,0,0,0,0,0,0,0,
  1,1,1,1,1,1,1,1,1,1,
  2,2,2,2,2,2,
  3,3,3,
  4};
static __device__ const int TJ[P3] = {
  1,1,1,1,1, 2,2,2,2, 3,3,3, 4,4, 5,
  2,2,2,2, 3,3,3, 4,4, 5,
  3,3,3, 4,4, 5,
  4,4, 5,
  5};
static __device__ const int TK[P3] = {
  2,3,4,5,6, 3,4,5,6, 4,5,6, 5,6, 6,
  3,4,5,6, 4,5,6, 5,6, 6,
  4,5,6, 5,6, 6,
  5,6, 6,
  6};

// pair index in lexicographic C(7,2) enumeration, a<b
__device__ __forceinline__ int pos2(int a, int b) {
  return a * 6 - (a * (a - 1)) / 2 + (b - a - 1);
}

// Kernel A: build the fused constant table into d_ws.
// cbuf[h*RSTR + j]      = W1[j][h]   (j in 0..6)   -- W1 transposed row
// cbuf[h*RSTR + 16 + o] = M[h][o]    (o in 0..34)
// where M[h][o] = W1[i,h]*W2[h,jk] - W1[j,h]*W2[h,ik] + W1[k,h]*W2[h,ij]
__global__ void build_tables(const float* __restrict__ W1,
                             const float* __restrict__ W2,
                             float* __restrict__ cbuf)
{
  const int tid = threadIdx.x;
  for (int idx = tid; idx < HD * DIM; idx += BLK) {
    int h = idx / DIM, j = idx - h * DIM;
    cbuf[h * RSTR + j] = W1[j * HD + h];
  }
  for (int idx = tid; idx < HD * P3; idx += BLK) {
    int h = idx / P3, o = idx - h * P3;
    int i = TI[o], j = TJ[o], k = TK[o];
    cbuf[h * RSTR + 16 + o] =
        W1[i * HD + h] * W2[h * P2 + pos2(j, k)]
      - W1[j * HD + h] * W2[h * P2 + pos2(i, k)]
      + W1[k * HD + h] * W2[h * P2 + pos2(i, j)];
  }
}

// Kernel B: out[b,:] = cos(x[b]·W1) @ M, with all constants read via
// wave-uniform (threadIdx-independent) addresses -> scalar loads -> SGPRs.
__global__ __launch_bounds__(BLK)
void dform_kernel(const float* __restrict__ x,
                  const float* __restrict__ cbuf,
                  float* __restrict__ out, int B)
{
  __shared__ float stage[BLK * P3];  // reused: x rows, then out rows

  const int tid = threadIdx.x;
  const long long base = (long long)blockIdx.x * BLK;
  int rows = B - (int)base;
  if (rows > BLK) rows = BLK;

  // --- stage x rows into LDS (coalesced float4 for full blocks) ---
  if (rows == BLK) {
    const float4* src = reinterpret_cast<const float4*>(x + base * DIM);
    float4* dst = reinterpret_cast<float4*>(stage);
    for (int i = tid; i < BLK * DIM / 4; i += BLK) dst[i] = src[i];
  } else {
    for (int i = tid; i < rows * DIM; i += BLK) stage[i] = x[base * DIM + i];
    // fill remainder so unconditional compute reads defined data
    for (int i = rows * DIM + tid; i < BLK * DIM; i += BLK) stage[i] = 0.f;
  }
  __syncthreads();

  // per-thread row of x (stride 7, coprime with 32 banks -> conflict-free)
  float xr[DIM];
  #pragma unroll
  for (int j = 0; j < DIM; ++j) xr[j] = stage[tid * DIM + j];

  float acc[P3];
  #pragma unroll
  for (int p = 0; p < P3; ++p) acc[p] = 0.f;

  // Unconditional (wave-uniform control flow) so cbuf loads stay scalar.
  #pragma unroll 2
  for (int h = 0; h < HD; ++h) {
    const float* __restrict__ row = cbuf + h * RSTR;
    float t = 0.f;
    #pragma unroll
    for (int j = 0; j < DIM; ++j) t = fmaf(xr[j], row[j], t);
    float c = __cosf(t);
    #pragma unroll
    for (int p = 0; p < P3; ++p) acc[p] = fmaf(c, row[16 + p], acc[p]);
  }
  __syncthreads();  // done reading stage-as-x

  if (tid < rows) {
    #pragma unroll
    for (int p = 0; p < P3; ++p) stage[tid * P3 + p] = acc[p];  // 2-way max: free
  }
  __syncthreads();

  // --- coalesced store ---
  if (rows == BLK) {
    float4* dst = reinterpret_cast<float4*>(out + base * P3);
    const float4* src = reinterpret_cast<const float4*>(stage);
    for (int i = tid; i < BLK * P3 / 4; i += BLK) dst[i] = src[i];
  } else {
    for (int i = tid; i < rows * P3; i += BLK) out[base * P3 + i] = stage[i];
  }
}

extern "C" void kernel_launch(void* const* d_in, const int* in_sizes, int n_in,
                              void* d_out, int out_size, void* d_ws, size_t ws_size,
                              hipStream_t stream) {
  const float* x  = (const float*)d_in[0];
  const float* W1 = (const float*)d_in[1];
  const float* W2 = (const float*)d_in[2];
  float* out  = (float*)d_out;
  float* cbuf = (float*)d_ws;  // needs HD*RSTR*4 = 8192 bytes
  const int B = in_sizes[0] / DIM;
  const int grid = (B + BLK - 1) / BLK;
  hipLaunchKernelGGL(build_tables, dim3(1), dim3(BLK), 0, stream, W1, W2, cbuf);
  hipLaunchKernelGGL(dform_kernel, dim3(grid), dim3(BLK), 0, stream, x, cbuf, out, B);
}

// Round 4
// 24.767 us; speedup vs baseline: 1.1762x; 1.1030x over previous
//
#include <hip/hip_runtime.h>

#define DIM 7
#define HD  32   // hidden width of W1
#define P2  21   // C(7,2)
#define P3  35   // C(7,3)
#define BLK 256
#define RPT 4              // rows per thread
#define ROWS (BLK * RPT)   // 1024 rows per block

// Lexicographic triples (i<j<k) from 7 — combination index -> (i,j,k)
static __device__ const int TI[P3] = {
  0,0,0,0,0,0,0,0,0,0,0,0,0,0,0,
  1,1,1,1,1,1,1,1,1,1,
  2,2,2,2,2,2,
  3,3,3,
  4};
static __device__ const int TJ[P3] = {
  1,1,1,1,1, 2,2,2,2, 3,3,3, 4,4, 5,
  2,2,2,2, 3,3,3, 4,4, 5,
  3,3,3, 4,4, 5,
  4,4, 5,
  5};
static __device__ const int TK[P3] = {
  2,3,4,5,6, 3,4,5,6, 4,5,6, 5,6, 6,
  3,4,5,6, 4,5,6, 5,6, 6,
  4,5,6, 5,6, 6,
  5,6, 6,
  6};

__device__ __forceinline__ int pos2(int a, int b) {
  return a * 6 - (a * (a - 1)) / 2 + (b - a - 1);
}

__global__ __launch_bounds__(BLK)
void dform_kernel(const float* __restrict__ x,
                  const float* __restrict__ W1,
                  const float* __restrict__ W2,
                  float* __restrict__ out, int B)
{
  __shared__ float sW1T[HD][8];    // [h][j], padded to 8 (32B rows)
  __shared__ float sM[HD][36];     // [h][o], padded to 36 (144B rows, 16B-aligned)
  __shared__ float stage[BLK * P3]; // 8960 floats: x rows (7168) then out chunks (8960)

  const int tid = threadIdx.x;

  // --- build constant tables in LDS (per block; trivial VALU, L3-broadcast reads) ---
  for (int idx = tid; idx < HD * DIM; idx += BLK) {
    int h = idx / DIM, j = idx - h * DIM;
    sW1T[h][j] = W1[j * HD + h];
  }
  for (int idx = tid; idx < HD * P3; idx += BLK) {
    int h = idx / P3, o = idx - h * P3;
    int i = TI[o], j = TJ[o], k = TK[o];
    sM[h][o] = W1[i * HD + h] * W2[h * P2 + pos2(j, k)]
             - W1[j * HD + h] * W2[h * P2 + pos2(i, k)]
             + W1[k * HD + h] * W2[h * P2 + pos2(i, j)];
  }

  const long long base = (long long)blockIdx.x * ROWS;
  int rows = B - (int)base;
  if (rows > ROWS) rows = ROWS;

  // --- stage 1024 x-rows into LDS, coalesced float4 (7168 floats = 1792 float4) ---
  if (rows == ROWS) {
    const float4* src = reinterpret_cast<const float4*>(x + base * DIM);
    float4* dst = reinterpret_cast<float4*>(stage);
    #pragma unroll
    for (int i = 0; i < ROWS * DIM / 4 / BLK; ++i)
      dst[tid + i * BLK] = src[tid + i * BLK];
  } else {
    for (int i = tid; i < rows * DIM; i += BLK) stage[i] = x[base * DIM + i];
    for (int i = rows * DIM + tid; i < ROWS * DIM; i += BLK) stage[i] = 0.f;
  }
  __syncthreads();

  // thread t owns local rows {t, t+256, t+512, t+768}; lane-stride 7 dwords: conflict-free
  float xr[RPT][DIM];
  #pragma unroll
  for (int c = 0; c < RPT; ++c)
    #pragma unroll
    for (int j = 0; j < DIM; ++j)
      xr[c][j] = stage[(c * BLK + tid) * DIM + j];

  float acc[RPT][P3];
  #pragma unroll
  for (int c = 0; c < RPT; ++c)
    #pragma unroll
    for (int p = 0; p < P3; ++p) acc[c][p] = 0.f;

  // --- main loop: constants read once per h (broadcast b128), reused for 4 rows ---
  for (int h = 0; h < HD; ++h) {
    const float4* wrow = reinterpret_cast<const float4*>(&sW1T[h][0]);
    float4 w0 = wrow[0], w1 = wrow[1];  // w1.w unused pad
    float wj[DIM] = {w0.x, w0.y, w0.z, w0.w, w1.x, w1.y, w1.z};

    float cc[RPT];
    #pragma unroll
    for (int c = 0; c < RPT; ++c) {
      float t = 0.f;
      #pragma unroll
      for (int j = 0; j < DIM; ++j) t = fmaf(xr[c][j], wj[j], t);
      cc[c] = __cosf(t);
    }

    const float4* mrow = reinterpret_cast<const float4*>(&sM[h][0]);
    #pragma unroll
    for (int q = 0; q < 8; ++q) {
      float4 m = mrow[q];
      #pragma unroll
      for (int c = 0; c < RPT; ++c) {
        acc[c][4*q+0] = fmaf(cc[c], m.x, acc[c][4*q+0]);
        acc[c][4*q+1] = fmaf(cc[c], m.y, acc[c][4*q+1]);
        acc[c][4*q+2] = fmaf(cc[c], m.z, acc[c][4*q+2]);
        acc[c][4*q+3] = fmaf(cc[c], m.w, acc[c][4*q+3]);
      }
    }
    {
      float4 m = mrow[8];  // .w = pad, never used
      #pragma unroll
      for (int c = 0; c < RPT; ++c) {
        acc[c][32] = fmaf(cc[c], m.x, acc[c][32]);
        acc[c][33] = fmaf(cc[c], m.y, acc[c][33]);
        acc[c][34] = fmaf(cc[c], m.z, acc[c][34]);
      }
    }
  }
  __syncthreads();  // done reading stage-as-x

  // --- output: 4 chunks of 256 rows, staged through LDS for coalesced float4 stores ---
  #pragma unroll
  for (int c = 0; c < RPT; ++c) {
    // lane-stride 35 dwords (35 ≡ 3 mod 32, gcd=1): conflict-free
    #pragma unroll
    for (int p = 0; p < P3; ++p) stage[tid * P3 + p] = acc[c][p];
    __syncthreads();

    const long long obase = (base + (long long)c * BLK) * P3;
    if (rows == ROWS) {
      float4* dst = reinterpret_cast<float4*>(out + obase);
      const float4* src = reinterpret_cast<const float4*>(stage);
      for (int i = tid; i < BLK * P3 / 4; i += BLK) dst[i] = src[i];  // 2240 float4
    } else {
      int cr = rows - c * BLK;
      if (cr > BLK) cr = BLK;
      if (cr < 0) cr = 0;
      for (int i = tid; i < cr * P3; i += BLK) out[obase + i] = stage[i];
    }
    __syncthreads();
  }
}

extern "C" void kernel_launch(void* const* d_in, const int* in_sizes, int n_in,
                              void* d_out, int out_size, void* d_ws, size_t ws_size,
                              hipStream_t stream) {
  const float* x  = (const float*)d_in[0];
  const float* W1 = (const float*)d_in[1];
  const float* W2 = (const float*)d_in[2];
  float* out = (float*)d_out;
  const int B = in_sizes[0] / DIM;
  const int grid = (B + ROWS - 1) / ROWS;  // 256 for B=262144
  hipLaunchKernelGGL(dform_kernel, dim3(grid), dim3(BLK), 0, stream,
                     x, W1, W2, out, B);
}

// Round 5
// 21.651 us; speedup vs baseline: 1.3455x; 1.1439x over previous
//
#include <hip/hip_runtime.h>

#define DIM 7
#define HD  32   // hidden width
#define P2  21   // C(7,2)
#define P3  35   // C(7,3)
#define BLK 256
#define NT  3    // 16-wide col tiles (48 cols, 35 used)
#define TPW 4    // 16-row tiles per wave

typedef __attribute__((ext_vector_type(8))) short short8v;  // 8 bf16 (4 VGPRs)
typedef __attribute__((ext_vector_type(4))) float float4v;  // MFMA accumulator

// Lexicographic triples (i<j<k) from 7 — combination index -> (i,j,k)
static __device__ const int TI[P3] = {
  0,0,0,0,0,0,0,0,0,0,0,0,0,0,0,
  1,1,1,1,1,1,1,1,1,1,
  2,2,2,2,2,2,
  3,3,3,
  4};
static __device__ const int TJ[P3] = {
  1,1,1,1,1, 2,2,2,2, 3,3,3, 4,4, 5,
  2,2,2,2, 3,3,3, 4,4, 5,
  3,3,3, 4,4, 5,
  4,4, 5,
  5};
static __device__ const int TK[P3] = {
  2,3,4,5,6, 3,4,5,6, 4,5,6, 5,6, 6,
  3,4,5,6, 4,5,6, 5,6, 6,
  4,5,6, 5,6, 6,
  5,6, 6,
  6};

__device__ __forceinline__ int pos2(int a, int b) {
  return a * 6 - (a * (a - 1)) / 2 + (b - a - 1);
}

// round-to-nearest-even f32 -> bf16 bits (finite inputs only)
__device__ __forceinline__ unsigned short f2bf(float f) {
  unsigned int u = __float_as_uint(f);
  u += 0x7fffu + ((u >> 16) & 1u);
  return (unsigned short)(u >> 16);
}
__device__ __forceinline__ float bf2f(unsigned short s) {
  return __uint_as_float(((unsigned int)s) << 16);
}

__global__ __launch_bounds__(BLK)
void dform_kernel(const float* __restrict__ x,
                  const float* __restrict__ W1,
                  const float* __restrict__ W2,
                  float* __restrict__ out, int B)
{
  // M split into bf16 hi/lo, stored col-major: Mhi[(col)*HD + k], col in 0..47
  __shared__ unsigned short Mhi[NT * 16 * HD];  // 3 KB
  __shared__ unsigned short Mlo[NT * 16 * HD];  // 3 KB

  const int tid  = threadIdx.x;
  const int lane = tid & 63;
  const int lrow = lane & 15;   // A row / B col / D col within tile
  const int lgrp = lane >> 4;   // 0..3 -> k-group, D row group

  // --- build M (hi/lo bf16) in LDS; pad cols 35..47 with zeros ---
  for (int idx = tid; idx < NT * 16 * HD; idx += BLK) {
    int col = idx >> 5;      // /HD
    int h   = idx & (HD - 1);
    float val = 0.f;
    if (col < P3) {
      int i = TI[col], j = TJ[col], k = TK[col];
      val = W1[i * HD + h] * W2[h * P2 + pos2(j, k)]
          - W1[j * HD + h] * W2[h * P2 + pos2(i, k)]
          + W1[k * HD + h] * W2[h * P2 + pos2(i, j)];
    }
    unsigned short hs = f2bf(val);
    Mhi[idx] = hs;
    Mlo[idx] = f2bf(val - bf2f(hs));
  }

  // --- per-lane W1 columns into registers: w1r[j][e] = W1[j][lgrp*8+e] ---
  const int h0 = lgrp * 8;
  float w1r[DIM][8];
  #pragma unroll
  for (int j = 0; j < DIM; ++j) {
    float4 p0 = *reinterpret_cast<const float4*>(&W1[j * HD + h0]);
    float4 p1 = *reinterpret_cast<const float4*>(&W1[j * HD + h0 + 4]);
    w1r[j][0] = p0.x; w1r[j][1] = p0.y; w1r[j][2] = p0.z; w1r[j][3] = p0.w;
    w1r[j][4] = p1.x; w1r[j][5] = p1.y; w1r[j][6] = p1.z; w1r[j][7] = p1.w;
  }

  __syncthreads();

  // --- B fragments (persistent): lane needs M[k = h0+e][col = c*16+lrow] ---
  short8v bhi[NT], blo[NT];
  #pragma unroll
  for (int c = 0; c < NT; ++c) {
    int off = (c * 16 + lrow) * HD + h0;  // byte-16 aligned
    bhi[c] = *reinterpret_cast<const short8v*>(&Mhi[off]);
    blo[c] = *reinterpret_cast<const short8v*>(&Mlo[off]);
  }

  // --- main loop: TPW row-tiles per wave ---
  const int gw = blockIdx.x * (BLK / 64) + (tid >> 6);  // global wave id
  const int tb = gw * TPW;

  for (int i = 0; i < TPW; ++i) {
    const int t = tb + i;
    if (t * 16 >= B) break;

    // A operand: lane computes cos(x[row] . W1[:, h0+e]) for its 8 h's
    int row = t * 16 + lrow;
    if (row >= B) row = B - 1;                  // clamp (tail safety)
    const int rbase = row * DIM;
    float4 a = *reinterpret_cast<const float4*>(&x[rbase]);       // x[0..3]
    float4 b = *reinterpret_cast<const float4*>(&x[rbase + 3]);   // x[3..6]
    float xr[DIM] = {a.x, a.y, a.z, a.w, b.y, b.z, b.w};

    short8v ahi, alo;
    #pragma unroll
    for (int e = 0; e < 8; ++e) {
      float tv = 0.f;
      #pragma unroll
      for (int j = 0; j < DIM; ++j) tv = fmaf(xr[j], w1r[j][e], tv);
      float cv = __cosf(tv);
      unsigned short hs = f2bf(cv);
      ahi[e] = (short)hs;
      alo[e] = (short)f2bf(cv - bf2f(hs));
    }

    float4v acc[NT];
    #pragma unroll
    for (int c = 0; c < NT; ++c) {
      acc[c][0] = 0.f; acc[c][1] = 0.f; acc[c][2] = 0.f; acc[c][3] = 0.f;
    }

    #pragma unroll
    for (int c = 0; c < NT; ++c) {
      acc[c] = __builtin_amdgcn_mfma_f32_16x16x32_bf16(ahi, bhi[c], acc[c], 0, 0, 0);
      acc[c] = __builtin_amdgcn_mfma_f32_16x16x32_bf16(ahi, blo[c], acc[c], 0, 0, 0);
      acc[c] = __builtin_amdgcn_mfma_f32_16x16x32_bf16(alo, bhi[c], acc[c], 0, 0, 0);
    }

    // D: col = lrow (+16c), row = lgrp*4 + r  [m89-verified layout]
    #pragma unroll
    for (int c = 0; c < NT; ++c) {
      const int col = c * 16 + lrow;
      #pragma unroll
      for (int r = 0; r < 4; ++r) {
        const int orow = t * 16 + lgrp * 4 + r;
        if (col < P3 && orow < B)
          out[orow * P3 + col] = acc[c][r];
      }
    }
  }
}

extern "C" void kernel_launch(void* const* d_in, const int* in_sizes, int n_in,
                              void* d_out, int out_size, void* d_ws, size_t ws_size,
                              hipStream_t stream) {
  const float* x  = (const float*)d_in[0];
  const float* W1 = (const float*)d_in[1];
  const float* W2 = (const float*)d_in[2];
  float* out = (float*)d_out;
  const int B = in_sizes[0] / DIM;
  const int ntiles = (B + 15) / 16;
  const int waves  = (ntiles + TPW - 1) / TPW;
  const int grid   = (waves + (BLK / 64) - 1) / (BLK / 64);  // 1024 for B=262144
  hipLaunchKernelGGL(dform_kernel, dim3(grid), dim3(BLK), 0, stream,
                     x, W1, W2, out, B);
}

// Round 6
// 19.825 us; speedup vs baseline: 1.4694x; 1.0921x over previous
//
#include <hip/hip_runtime.h>

#define DIM 7
#define HD  32   // hidden width
#define P2  21   // C(7,2)
#define P3  35   // C(7,3)
#define BLK 256
#define NT  3    // 16-wide output-col tiles (48 cols, 35 used)
#define TPW 4    // 16-row tiles per wave

typedef __attribute__((ext_vector_type(8))) _Float16 half8v;  // MFMA A/B operand
typedef __attribute__((ext_vector_type(4))) float  float4v;   // MFMA accumulator

// Lexicographic triples (i<j<k) from 7 — combination index -> (i,j,k)
static __device__ const int TI[P3] = {
  0,0,0,0,0,0,0,0,0,0,0,0,0,0,0,
  1,1,1,1,1,1,1,1,1,1,
  2,2,2,2,2,2,
  3,3,3,
  4};
static __device__ const int TJ[P3] = {
  1,1,1,1,1, 2,2,2,2, 3,3,3, 4,4, 5,
  2,2,2,2, 3,3,3, 4,4, 5,
  3,3,3, 4,4, 5,
  4,4, 5,
  5};
static __device__ const int TK[P3] = {
  2,3,4,5,6, 3,4,5,6, 4,5,6, 5,6, 6,
  3,4,5,6, 4,5,6, 5,6, 6,
  4,5,6, 5,6, 6,
  5,6, 6,
  6};

__device__ __forceinline__ int pos2(int a, int b) {
  return a * 6 - (a * (a - 1)) / 2 + (b - a - 1);
}

__global__ __launch_bounds__(BLK)
void dform_kernel(const float* __restrict__ x,
                  const float* __restrict__ W1,
                  const float* __restrict__ W2,
                  float* __restrict__ out, int B)
{
  // M as f16, col-major: Mh[col*HD + h], cols 0..47 (35..47 zero-pad). 3 KB.
  __shared__ _Float16 Mh[NT * 16 * HD];

  const int tid  = threadIdx.x;
  const int lane = tid & 63;
  const int lrow = lane & 15;   // out row within tile (= D col)
  const int lgrp = lane >> 4;   // k-group; D-row group (= out col group)

  // --- build M in LDS ---
  for (int idx = tid; idx < NT * 16 * HD; idx += BLK) {
    int col = idx >> 5;      // / HD
    int h   = idx & (HD - 1);
    float val = 0.f;
    if (col < P3) {
      int i = TI[col], j = TJ[col], k = TK[col];
      val = W1[i * HD + h] * W2[h * P2 + pos2(j, k)]
          - W1[j * HD + h] * W2[h * P2 + pos2(i, k)]
          + W1[k * HD + h] * W2[h * P2 + pos2(i, j)];
    }
    Mh[idx] = (_Float16)val;
  }

  // --- per-lane W1 columns: w1r[j][e] = W1[j][h0+e] ---
  const int h0 = lgrp * 8;
  float w1r[DIM][8];
  #pragma unroll
  for (int j = 0; j < DIM; ++j) {
    float4 p0 = *reinterpret_cast<const float4*>(&W1[j * HD + h0]);
    float4 p1 = *reinterpret_cast<const float4*>(&W1[j * HD + h0 + 4]);
    w1r[j][0] = p0.x; w1r[j][1] = p0.y; w1r[j][2] = p0.z; w1r[j][3] = p0.w;
    w1r[j][4] = p1.x; w1r[j][5] = p1.y; w1r[j][6] = p1.z; w1r[j][7] = p1.w;
  }

  __syncthreads();

  // --- A-operand fragments (persistent): A[i=p][k=h] = M[h][p], p = c*16+lrow ---
  half8v mfrag[NT];
  #pragma unroll
  for (int c = 0; c < NT; ++c) {
    int off = (c * 16 + lrow) * HD + h0;   // *2B -> 16B aligned
    mfrag[c] = *reinterpret_cast<const half8v*>(&Mh[off]);
  }

  const int gw = blockIdx.x * (BLK / 64) + (tid >> 6);  // global wave id
  const int tb = gw * TPW;

  // --- prefetch x rows for all TPW tiles (hide HBM latency) ---
  float xr[TPW][DIM];
  #pragma unroll
  for (int i = 0; i < TPW; ++i) {
    int row = (tb + i) * 16 + lrow;
    if (row >= B) row = B - 1;   // clamp; tail guarded at store
    const int rbase = row * DIM;
    float4 a = *reinterpret_cast<const float4*>(&x[rbase]);
    float4 b = *reinterpret_cast<const float4*>(&x[rbase + 3]);
    xr[i][0] = a.x; xr[i][1] = a.y; xr[i][2] = a.z; xr[i][3] = a.w;
    xr[i][4] = b.y; xr[i][5] = b.z; xr[i][6] = b.w;
  }

  #pragma unroll
  for (int i = 0; i < TPW; ++i) {
    const int t = tb + i;
    if (t * 16 >= B) break;

    // B-operand: B[k=h0+e][j=lrow] = cos(x[row] . W1[:,h0+e])
    half8v cfrag;
    #pragma unroll
    for (int e = 0; e < 8; ++e) {
      float tv = 0.f;
      #pragma unroll
      for (int j = 0; j < DIM; ++j) tv = fmaf(xr[i][j], w1r[j][e], tv);
      cfrag[e] = (_Float16)__cosf(tv);
    }

    // D = M^T · cos^T = out^T-tile: lane holds out[row=t*16+lrow][c*16+lgrp*4+r]
    float4v acc[NT];
    #pragma unroll
    for (int c = 0; c < NT; ++c) {
      acc[c][0] = 0.f; acc[c][1] = 0.f; acc[c][2] = 0.f; acc[c][3] = 0.f;
      acc[c] = __builtin_amdgcn_mfma_f32_16x16x32_f16(mfrag[c], cfrag, acc[c], 0, 0, 0);
    }

    const int row = t * 16 + lrow;
    if (row < B) {
      float* op = out + (long long)row * P3;
      const int cb = lgrp * 4;
      // cols cb..cb+3 and 16+cb..16+cb+3: consecutive -> dwordx4
      *reinterpret_cast<float4*>(op + cb) =
          make_float4(acc[0][0], acc[0][1], acc[0][2], acc[0][3]);
      *reinterpret_cast<float4*>(op + 16 + cb) =
          make_float4(acc[1][0], acc[1][1], acc[1][2], acc[1][3]);
      if (lgrp == 0) {  // cols 32..34 (35+ are pad)
        *reinterpret_cast<float2*>(op + 32) = make_float2(acc[2][0], acc[2][1]);
        op[34] = acc[2][2];
      }
    }
  }
}

extern "C" void kernel_launch(void* const* d_in, const int* in_sizes, int n_in,
                              void* d_out, int out_size, void* d_ws, size_t ws_size,
                              hipStream_t stream) {
  const float* x  = (const float*)d_in[0];
  const float* W1 = (const float*)d_in[1];
  const float* W2 = (const float*)d_in[2];
  float* out = (float*)d_out;
  const int B = in_sizes[0] / DIM;
  const int ntiles = (B + 15) / 16;
  const int waves  = (ntiles + TPW - 1) / TPW;
  const int grid   = (waves + (BLK / 64) - 1) / (BLK / 64);  // 1024 for B=262144
  hipLaunchKernelGGL(dform_kernel, dim3(grid), dim3(BLK), 0, stream,
                     x, W1, W2, out, B);
}

// Round 7
// 19.485 us; speedup vs baseline: 1.4950x; 1.0175x over previous
//
#include <hip/hip_runtime.h>

#define DIM 7
#define HD  32   // hidden width
#define P2  21   // C(7,2)
#define P3  35   // C(7,3)
#define BLK 256
#define NT  3    // 16-wide output-col tiles (48 cols, 35 used)
#define TPW 4    // 16-row tiles per wave
#define WPB (BLK / 64)
#define WSLAB (TPW * 16 * DIM)   // 448 floats of x per wave

typedef __attribute__((ext_vector_type(8))) _Float16 half8v;  // MFMA A/B operand
typedef __attribute__((ext_vector_type(4))) float  float4v;   // MFMA accumulator

// Lexicographic triples (i<j<k) from 7 — combination index -> (i,j,k)
static __device__ const int TI[P3] = {
  0,0,0,0,0,0,0,0,0,0,0,0,0,0,0,
  1,1,1,1,1,1,1,1,1,1,
  2,2,2,2,2,2,
  3,3,3,
  4};
static __device__ const int TJ[P3] = {
  1,1,1,1,1, 2,2,2,2, 3,3,3, 4,4, 5,
  2,2,2,2, 3,3,3, 4,4, 5,
  3,3,3, 4,4, 5,
  4,4, 5,
  5};
static __device__ const int TK[P3] = {
  2,3,4,5,6, 3,4,5,6, 4,5,6, 5,6, 6,
  3,4,5,6, 4,5,6, 5,6, 6,
  4,5,6, 5,6, 6,
  5,6, 6,
  6};

__device__ __forceinline__ int pos2(int a, int b) {
  return a * 6 - (a * (a - 1)) / 2 + (b - a - 1);
}

__global__ __launch_bounds__(BLK)
void dform_kernel(const float* __restrict__ x,
                  const float* __restrict__ W1,
                  const float* __restrict__ W2,
                  float* __restrict__ out, int B)
{
  // M as f16, col-major: Mh[col*HD + h], cols 0..47 (35..47 zero-pad). 3 KB.
  __shared__ _Float16 Mh[NT * 16 * HD];
  // per-wave x slab: 4 waves x 448 floats = 7 KB
  __shared__ float xs[WPB * WSLAB];

  const int tid  = threadIdx.x;
  const int lane = tid & 63;
  const int wid  = tid >> 6;
  const int lrow = lane & 15;   // out row within tile (= D col)
  const int lgrp = lane >> 4;   // k-group; D-row group (= out col group)

  // --- build M in LDS ---
  for (int idx = tid; idx < NT * 16 * HD; idx += BLK) {
    int col = idx >> 5;      // / HD
    int h   = idx & (HD - 1);
    float val = 0.f;
    if (col < P3) {
      int i = TI[col], j = TJ[col], k = TK[col];
      val = W1[i * HD + h] * W2[h * P2 + pos2(j, k)]
          - W1[j * HD + h] * W2[h * P2 + pos2(i, k)]
          + W1[k * HD + h] * W2[h * P2 + pos2(i, j)];
    }
    Mh[idx] = (_Float16)val;
  }

  // --- per-lane W1 columns: w1r[j][e] = W1[j][h0+e] ---
  const int h0 = lgrp * 8;
  float w1r[DIM][8];
  #pragma unroll
  for (int j = 0; j < DIM; ++j) {
    float4 p0 = *reinterpret_cast<const float4*>(&W1[j * HD + h0]);
    float4 p1 = *reinterpret_cast<const float4*>(&W1[j * HD + h0 + 4]);
    w1r[j][0] = p0.x; w1r[j][1] = p0.y; w1r[j][2] = p0.z; w1r[j][3] = p0.w;
    w1r[j][4] = p1.x; w1r[j][5] = p1.y; w1r[j][6] = p1.z; w1r[j][7] = p1.w;
  }

  // --- stage this wave's x slab: aligned, coalesced, deduplicated ---
  const int gw = blockIdx.x * WPB + wid;        // global wave id
  const int tb = gw * TPW;                      // first tile of this wave
  const long long xbase = (long long)gw * WSLAB;  // float index into x
  float* xw = xs + wid * WSLAB;
  if (xbase + WSLAB <= (long long)B * DIM) {
    const float4* src = reinterpret_cast<const float4*>(x + xbase);  // 16B-aligned
    float4* dst = reinterpret_cast<float4*>(xw);
    dst[lane] = src[lane];
    if (lane < WSLAB / 4 - 64) dst[lane + 64] = src[lane + 64];  // lanes 0..47
  } else {
    for (int i = lane; i < WSLAB; i += 64) {
      long long g = xbase + i;
      xw[i] = (g < (long long)B * DIM) ? x[g] : 0.f;
    }
  }

  __syncthreads();  // M table ready (also drains the xs writes)

  // --- A-operand fragments (persistent): A[i=p][k=h] = M[h][p], p = c*16+lrow ---
  half8v mfrag[NT];
  #pragma unroll
  for (int c = 0; c < NT; ++c) {
    int off = (c * 16 + lrow) * HD + h0;   // *2B -> 16B aligned
    mfrag[c] = *reinterpret_cast<const half8v*>(&Mh[off]);
  }

  // --- per-tile x rows from LDS: bank = (lrow*7+j)%32, 16 banks, 4-lane broadcast ---
  float xr[TPW][DIM];
  #pragma unroll
  for (int i = 0; i < TPW; ++i)
    #pragma unroll
    for (int j = 0; j < DIM; ++j)
      xr[i][j] = xw[(i * 16 + lrow) * DIM + j];

  #pragma unroll
  for (int i = 0; i < TPW; ++i) {
    const int t = tb + i;
    if (t * 16 >= B) break;

    // B-operand: B[k=h0+e][j=lrow] = cos(x[row] . W1[:,h0+e])
    half8v cfrag;
    #pragma unroll
    for (int e = 0; e < 8; ++e) {
      float tv = 0.f;
      #pragma unroll
      for (int j = 0; j < DIM; ++j) tv = fmaf(xr[i][j], w1r[j][e], tv);
      cfrag[e] = (_Float16)__cosf(tv);
    }

    // D = M^T · cos^T: lane holds out[row=t*16+lrow][c*16 + lgrp*4 + r]
    float4v acc[NT];
    #pragma unroll
    for (int c = 0; c < NT; ++c) {
      acc[c][0] = 0.f; acc[c][1] = 0.f; acc[c][2] = 0.f; acc[c][3] = 0.f;
      acc[c] = __builtin_amdgcn_mfma_f32_16x16x32_f16(mfrag[c], cfrag, acc[c], 0, 0, 0);
    }

    const int row = t * 16 + lrow;
    if (row < B) {
      float* op = out + (long long)row * P3;
      const int cb = lgrp * 4;
      *reinterpret_cast<float4*>(op + cb) =
          make_float4(acc[0][0], acc[0][1], acc[0][2], acc[0][3]);
      *reinterpret_cast<float4*>(op + 16 + cb) =
          make_float4(acc[1][0], acc[1][1], acc[1][2], acc[1][3]);
      if (lgrp == 0) {  // cols 32..34 (35+ are pad)
        *reinterpret_cast<float2*>(op + 32) = make_float2(acc[2][0], acc[2][1]);
        op[34] = acc[2][2];
      }
    }
  }
}

extern "C" void kernel_launch(void* const* d_in, const int* in_sizes, int n_in,
                              void* d_out, int out_size, void* d_ws, size_t ws_size,
                              hipStream_t stream) {
  const float* x  = (const float*)d_in[0];
  const float* W1 = (const float*)d_in[1];
  const float* W2 = (const float*)d_in[2];
  float* out = (float*)d_out;
  const int B = in_sizes[0] / DIM;
  const int ntiles = (B + 15) / 16;
  const int waves  = (ntiles + TPW - 1) / TPW;
  const int grid   = (waves + WPB - 1) / WPB;  // 1024 for B=262144
  hipLaunchKernelGGL(dform_kernel, dim3(grid), dim3(BLK), 0, stream,
                     x, W1, W2, out, B);
}